// Round 8
// baseline (162.459 us; speedup 1.0000x reference)
//
#include <hip/hip_runtime.h>
#include <hip/hip_fp16.h>

#define N_NODES  100000
#define N_EDGES  1000000
#define N_GRAPHS 2048
#define IN_DIM   5
#define HIDDEN   64
#define OUT_DIM  128
#define CAP      32    // bucket capacity; in-degree ~ Poisson(10), P(>=33)~5e-9/node
#define NA       512   // blocks in partition pass
#define PART     256   // nodes per partition (= 2^8, matches dst>>8)
#define NBIN     391   // ceil(N_NODES/PART)
#define CAPBIN   4096  // epart slab per bin (>>10 sigma of Binom bin count)
#define LSTR     72    // LDS row stride in halves (144 B: 16B-aligned, 2-way banks)
#define MAXN     192   // max nodes/graph for degree sort (mean 48.8, sd 7)
#define NSTG     96    // max nodes/graph for LDS bucket staging (6.7 sigma)
#define EPT      8     // edges per thread in k_part2 (ceil(1M/131072))

typedef _Float16 f16x8 __attribute__((ext_vector_type(8)));
typedef float    f32x4 __attribute__((ext_vector_type(4)));

// ---------------------------------------------------------------------------
// NOTE (R3): device-scope atomic cnt + dependent scattered 4B stores = 85us
// (write-allocate thrash).  Keep the LDS multisplit.  Do not re-try.
// NOTE (R5): launch-count reduction was NEUTRAL (graph capture).
// NOTE (R6): degree-sorted node order won ~4.6us (wave divergence).
// NOTE (R7): LDS bucket staging won ~2.8us (index loads off critical path).
// R8: k_g2ph is in-flight-limited on L3-latency gathers (hs2h 12.8MB > 4MB
// per-XCD L2).  Dual-node interleave: each 8-lane group processes two
// adjacent-rank (degree-sorted) nodes, 16 loads in flight in the joint tier.
// ---------------------------------------------------------------------------

// pass A: fused {graph-ranges + per-block histogram + slab reserve + scatter}.
// Edges register-cached between passes: each thread owns <= EPT edges.
__global__ void __launch_bounds__(256) k_part2(
        const int* __restrict__ src, const int* __restrict__ dst,
        const int* __restrict__ batch, int* __restrict__ gcursor,
        int* __restrict__ epart, int* __restrict__ gs) {
    __shared__ int h[NBIN];
    __shared__ int off[NBIN];
    int t = threadIdx.x, b = blockIdx.x;

    // folded k_ranges: gs[g] = first node with batch >= g (batch sorted)
    int gid = b * 256 + t;
    if (gid < N_NODES) {
        int bi = batch[gid];
        int bp = (gid == 0) ? -1 : batch[gid - 1];
        for (int g = bp + 1; g <= bi; g++) gs[g] = gid;
        if (gid == N_NODES - 1)
            for (int g = bi + 1; g <= N_GRAPHS; g++) gs[g] = N_NODES;
    }

    for (int i = t; i < NBIN; i += 256) h[i] = 0;
    __syncthreads();
    int ebin[EPT], epay[EPT];
    int ebase = b * 256 + t;
#pragma unroll
    for (int i = 0; i < EPT; i++) {
        int e = ebase + i * (NA * 256);
        ebin[i] = -1;
        if (e < N_EDGES) {
            int d = dst[e];
            ebin[i] = d >> 8;
            epay[i] = ((d & (PART - 1)) << 17) | src[e];
            atomicAdd(&h[ebin[i]], 1);              // LDS atomic
        }
    }
    __syncthreads();
    for (int i = t; i < NBIN; i += 256) {
        int c = h[i];
        int base = c ? atomicAdd(&gcursor[i], c) : 0;   // global slab reserve
        off[i] = i * CAPBIN + base;
    }
    __syncthreads();
#pragma unroll
    for (int i = 0; i < EPT; i++) {
        if (ebin[i] >= 0) {
            int pos = atomicAdd(&off[ebin[i]], 1);  // LDS cursor
            if (pos < (ebin[i] + 1) * CAPBIN)       // overflow guard (~1e-20)
                epart[pos] = epay[i];
        }
    }
}

// pass B: per-partition bucket build fully in LDS + fused prep (dinv, xs fp16)
__global__ void __launch_bounds__(256) k_build(
        const int* __restrict__ epart, const int* __restrict__ bincnt,
        const float* __restrict__ x, int* __restrict__ cnt, int* __restrict__ bkt,
        float* __restrict__ dinv, __half* __restrict__ xs) {
    __shared__ int lcnt[PART];
    __shared__ int lrows[PART * CAP];               // 32 KB
    int t = threadIdx.x, b = blockIdx.x;
    int base = b * PART;
    for (int i = t; i < PART; i += 256) lcnt[i] = 0;
    __syncthreads();
    int estart = b * CAPBIN;
    int eend = estart + min(bincnt[b], CAPBIN);
    for (int i = estart + t; i < eend; i += 256) {
        int ed = epart[i];
        int ln = ed >> 17;
        int c = atomicAdd(&lcnt[ln], 1);            // LDS atomic
        if (c < CAP) lrows[ln * CAP + c] = ed & 0x1FFFF;
    }
    __syncthreads();
    int gbase = base * CAP;
    int lim = min(PART * CAP, N_NODES * CAP - gbase);
    for (int i = t; i < lim; i += 256) bkt[gbase + i] = lrows[i];
    for (int n = t; n < PART; n += 256) {
        int g = base + n;
        if (g < N_NODES) {
            int c = lcnt[n];
            cnt[g] = c;
            float d = rsqrtf(1.0f + (float)c);
            dinv[g] = d;
            union { __half h[8]; float4 f4; } u;
#pragma unroll
            for (int k = 0; k < 8; k++)
                u.h[k] = __float2half((k < IN_DIM) ? x[g * IN_DIM + k] * d : 0.0f);
            ((float4*)xs)[g] = u.f4;                // one 16B store
        }
    }
}

// fused layer-1 gather + layer-1 linear + layer-2 linear (MFMA). 64 nodes/block.
// Degree-sorted node order; block's 64 bkt rows staged into the (temporally
// dead) lh1 LDS region via one coalesced sweep.
__global__ void __launch_bounds__(256) k_g5l12(
        const int* __restrict__ cnt, const int* __restrict__ bkt,
        const __half* __restrict__ xs,
        const float* __restrict__ W1, const float* __restrict__ b1,
        const float* __restrict__ W2, const float* __restrict__ dinv,
        __half* __restrict__ hs2h) {
    __shared__ __align__(16) _Float16 lh1[64 * LSTR];   // h1 (phase>=1); bkt stage (phase A)
    __shared__ __align__(16) _Float16 lw2[64 * LSTR];   // W2 transposed: lw2[n*LSTR + k]
    __shared__ float la5[64][8];          // aggregated layer-1 input
    __shared__ unsigned short ordn[64];   // degree-sorted node permutation
    __shared__ int dsh[CAP + 1];
    __shared__ int sdeg[64];
    int tid = threadIdx.x;
    int w = tid >> 6, l = tid & 63;
    int nodeBase = blockIdx.x * 64;

    // W2 staging: 4 float4 loads/thread (was 16 scalar loads)
#pragma unroll
    for (int i = 0; i < 4; i++) {
        int idx = tid + i * 256;          // 0..1023 float4s
        float4 wv = ((const float4*)W2)[idx];
        int k = idx >> 4, n4 = (idx & 15) * 4;
        lw2[(n4 + 0) * LSTR + k] = (_Float16)wv.x;
        lw2[(n4 + 1) * LSTR + k] = (_Float16)wv.y;
        lw2[(n4 + 2) * LSTR + k] = (_Float16)wv.z;
        lw2[(n4 + 3) * LSTR + k] = (_Float16)wv.w;
    }

    // stage this block's 64 bkt rows (8 KB contiguous) into lh1's space
    int* sbkt5 = (int*)lh1;               // 64*CAP ints = 8 KB (lh1 is 9.2 KB)
    {
        const int4* gb = (const int4*)(bkt + (size_t)nodeBase * CAP);
        int4* sb = (int4*)sbkt5;
        int lim4 = min(64, N_NODES - nodeBase) * (CAP / 4);
        for (int i = tid; i < lim4; i += 256) sb[i] = gb[i];
    }

    // counting sort of the block's 64 nodes by degree
    if (tid <= CAP) dsh[tid] = 0;
    __syncthreads();
    int mydeg = 0;
    if (tid < 64) {
        int g = nodeBase + tid;
        mydeg = (g < N_NODES) ? min(cnt[g], CAP) : 0;
        sdeg[tid] = mydeg;
        atomicAdd(&dsh[mydeg], 1);
    }
    __syncthreads();
    if (tid == 0) {
        int acc = 0;
        for (int i = 0; i <= CAP; i++) { int c = dsh[i]; dsh[i] = acc; acc += c; }
    }
    __syncthreads();
    if (tid < 64) { int pos = atomicAdd(&dsh[mydeg], 1); ordn[pos] = tid; }
    __syncthreads();   // also covers sbkt5 staging

    // phase A: 4 lanes per node split the edge list; indices from LDS;
    // each lane loads the FULL 16B xs row (float4); shfl butterfly merge.
    {
        int g4 = l >> 2, l4 = l & 3;      // node-in-wave, lane-in-node
        int lnm = ordn[w * 16 + g4];      // degree-sorted assignment
        int g = nodeBase + lnm;
        float s0 = 0.f, s1 = 0.f, s2 = 0.f, s3 = 0.f;
        float s4 = 0.f, s5 = 0.f, s6 = 0.f, s7 = 0.f;
        if (g < N_NODES) {
            const float4* XS4 = (const float4*)xs;   // one row = one float4
            int len = sdeg[lnm];
            const int* row = sbkt5 + lnm * CAP;      // LDS indices
#define XACC(r) { const __half2* hp_ = (const __half2*)&(r);                   \
            float2 u0_ = __half22float2(hp_[0]), u1_ = __half22float2(hp_[1]); \
            float2 u2_ = __half22float2(hp_[2]), u3_ = __half22float2(hp_[3]); \
            s0 += u0_.x; s1 += u0_.y; s2 += u1_.x; s3 += u1_.y;                \
            s4 += u2_.x; s5 += u2_.y; s6 += u3_.x; s7 += u3_.y; }
            int e = l4;
            for (; e + 4 < len; e += 8) {            // 2 outstanding 16B loads
                float4 r0 = XS4[row[e]];
                float4 r1 = XS4[row[e + 4]];
                XACC(r0); XACC(r1);
            }
            if (e < len) { float4 r0 = XS4[row[e]]; XACC(r0); }
            if (l4 == 0) { float4 rs = XS4[g]; XACC(rs); }   // self loop
#undef XACC
        }
        // merge the 4 lane-partials of each node (lane bits 0,1)
#pragma unroll
        for (int m = 1; m <= 2; m <<= 1) {
            s0 += __shfl_xor(s0, m); s1 += __shfl_xor(s1, m);
            s2 += __shfl_xor(s2, m); s3 += __shfl_xor(s3, m);
            s4 += __shfl_xor(s4, m); s5 += __shfl_xor(s5, m);
            s6 += __shfl_xor(s6, m); s7 += __shfl_xor(s7, m);
        }
        if (l4 == 0) {
            float d = (g < N_NODES) ? dinv[g] : 0.f;
            la5[lnm][0] = s0 * d; la5[lnm][1] = s1 * d;
            la5[lnm][2] = s2 * d; la5[lnm][3] = s3 * d;
            la5[lnm][4] = s4 * d; la5[lnm][5] = s5 * d;
            la5[lnm][6] = s6 * d; la5[lnm][7] = s7 * d;
        }
    }
    __syncthreads();   // la5 cross-wave; sbkt5 reads done -> lh1 reusable

    // phase 1: wave w computes h1 for its 16 nodes, lane = feature
    int f = l;
    float b1v = b1[f];
    float w1v[IN_DIM];
#pragma unroll
    for (int k = 0; k < IN_DIM; k++) w1v[k] = W1[k * HIDDEN + f];
    for (int i = 0; i < 16; i++) {
        int ln = w * 16 + i;
        float t1 = b1v;
#pragma unroll
        for (int k = 0; k < IN_DIM; k++)
            t1 += la5[ln][k] * w1v[k];
        lh1[ln * LSTR + f] = (_Float16)fmaxf(t1, 0.f);
    }
    __syncthreads();

    // phase 2: wave w owns row-block w (16 nodes) x 4 col-tiles, K=64
    int quad = l >> 4, m16 = l & 15;
    f32x4 acc0 = {0.f, 0.f, 0.f, 0.f};
    f32x4 acc1 = {0.f, 0.f, 0.f, 0.f};
    f32x4 acc2 = {0.f, 0.f, 0.f, 0.f};
    f32x4 acc3 = {0.f, 0.f, 0.f, 0.f};
#pragma unroll
    for (int kc = 0; kc < 2; kc++) {
        f16x8 a = *(const f16x8*)&lh1[(w * 16 + m16) * LSTR + kc * 32 + quad * 8];
        f16x8 b0 = *(const f16x8*)&lw2[(0 * 16 + m16) * LSTR + kc * 32 + quad * 8];
        f16x8 b1f = *(const f16x8*)&lw2[(1 * 16 + m16) * LSTR + kc * 32 + quad * 8];
        f16x8 b2 = *(const f16x8*)&lw2[(2 * 16 + m16) * LSTR + kc * 32 + quad * 8];
        f16x8 b3 = *(const f16x8*)&lw2[(3 * 16 + m16) * LSTR + kc * 32 + quad * 8];
        acc0 = __builtin_amdgcn_mfma_f32_16x16x32_f16(a, b0, acc0, 0, 0, 0);
        acc1 = __builtin_amdgcn_mfma_f32_16x16x32_f16(a, b1f, acc1, 0, 0, 0);
        acc2 = __builtin_amdgcn_mfma_f32_16x16x32_f16(a, b2, acc2, 0, 0, 0);
        acc3 = __builtin_amdgcn_mfma_f32_16x16x32_f16(a, b3, acc3, 0, 0, 0);
    }
#pragma unroll
    for (int i = 0; i < 4; i++) {
        int g = nodeBase + w * 16 + quad * 4 + i;
        if (g >= N_NODES) continue;
        float dv = dinv[g];
        __half* row = hs2h + (size_t)g * HIDDEN + m16;
        row[0]  = __float2half(acc0[i] * dv);
        row[16] = __float2half(acc1[i] * dv);
        row[32] = __float2half(acc2[i] * dv);
        row[48] = __float2half(acc3[i] * dv);
    }
}

// layer-2 gather + relu+b2 + pool + FUSED HEAD MLP.  Graph-per-block,
// register pooling, zero atomics, degree-sorted order, LDS-staged buckets,
// and DUAL-NODE interleaved gathers (16 loads in flight in the joint tier).
__global__ void __launch_bounds__(256) k_g2ph(
        const int* __restrict__ cnt, const int* __restrict__ bkt,
        const __half* __restrict__ hs2h, const float* __restrict__ dinv,
        const int* __restrict__ gs, const float* __restrict__ b2,
        const float* __restrict__ W3, const float* __restrict__ b3,
        const float* __restrict__ W4, const float* __restrict__ b4,
        float* __restrict__ out) {
    __shared__ __align__(16) int sbkt[NSTG][CAP];   // 12 KB staged indices
    __shared__ int   scnt[NSTG];
    __shared__ float sdinv[NSTG];
    __shared__ float pool[4][HIDDEN];               // 1 KB
    __shared__ float gp[HIDDEN];
    __shared__ float gz[HIDDEN];
    __shared__ unsigned short ord[MAXN];
    __shared__ int dsh[CAP + 1];
    int g = blockIdx.x, tid = threadIdx.x;
    int grp = tid >> 3, l8 = tid & 7;               // 32 groups x 8 lanes
    int w = tid >> 6;
    int s = gs[g], e = gs[g + 1];
    int n = e - s;
    int nst = min(n, NSTG);
    bool dosort = (n <= MAXN);

    // coalesced stage of the graph's bucket slab + cnt + dinv
    {
        const int4* gb = (const int4*)(bkt + (size_t)s * CAP);
        int4* sb = (int4*)&sbkt[0][0];
        int tot = nst * (CAP / 4);
        for (int i = tid; i < tot; i += 256) sb[i] = gb[i];
    }
    for (int i = tid; i < nst; i += 256) {
        scnt[i]  = min(cnt[s + i], CAP);
        sdinv[i] = dinv[s + i];
    }
    if (tid <= CAP) dsh[tid] = 0;
    __syncthreads();

    // counting sort of the graph's nodes by degree (order-free reductions)
    int mydeg = 0;
    if (dosort && tid < n) {
        mydeg = (tid < nst) ? scnt[tid] : min(cnt[s + tid], CAP);
        atomicAdd(&dsh[mydeg], 1);
    }
    __syncthreads();
    if (tid == 0) {
        int acc = 0;
        for (int i = 0; i <= CAP; i++) { int c = dsh[i]; dsh[i] = acc; acc += c; }
    }
    __syncthreads();
    if (dosort && tid < n) { int pos = atomicAdd(&dsh[mydeg], 1); ord[pos] = tid; }
    __syncthreads();

    const float4* H16 = (const float4*)hs2h;        // row = 8 float4 (aligned)
    float4 b2a = ((const float4*)b2)[l8 * 2];
    float4 b2b = ((const float4*)b2)[l8 * 2 + 1];
    float p0 = 0.f, p1 = 0.f, p2 = 0.f, p3 = 0.f;
    float p4 = 0.f, p5 = 0.f, p6 = 0.f, p7 = 0.f;

#define ACCV(A0,A1,A2,A3,A4,A5,A6,A7, r) { const __half2* hp_ = (const __half2*)&(r); \
        float2 u0_ = __half22float2(hp_[0]), u1_ = __half22float2(hp_[1]);            \
        float2 u2_ = __half22float2(hp_[2]), u3_ = __half22float2(hp_[3]);            \
        A0 += u0_.x; A1 += u0_.y; A2 += u1_.x; A3 += u1_.y;                           \
        A4 += u2_.x; A5 += u2_.y; A6 += u3_.x; A7 += u3_.y; }
#define ACCA(r) ACCV(a0,a1,a2,a3,a4,a5,a6,a7, r)
#define ACCB(r) ACCV(q0,q1,q2,q3,q4,q5,q6,q7, r)
#define LD4A(e0) int4 iA = *(const int4*)&(rowA)[e0];            \
        float4 rA0 = H16[(size_t)iA.x * 8 + l8];                 \
        float4 rA1 = H16[(size_t)iA.y * 8 + l8];                 \
        float4 rA2 = H16[(size_t)iA.z * 8 + l8];                 \
        float4 rA3 = H16[(size_t)iA.w * 8 + l8];
#define LD4B(e0) int4 iB = *(const int4*)&(rowB)[e0];            \
        float4 rB0 = H16[(size_t)iB.x * 8 + l8];                 \
        float4 rB1 = H16[(size_t)iB.y * 8 + l8];                 \
        float4 rB2 = H16[(size_t)iB.z * 8 + l8];                 \
        float4 rB3 = H16[(size_t)iB.w * 8 + l8];

#define DUAL_BODY(ROWA, LENA, DVA, NODEA, HASB, ROWB, LENB, DVB, NODEB)        \
    {                                                                          \
        const int* rowA = (ROWA);                                              \
        const int* rowB = (ROWB);                                              \
        int lenA = (LENA);                                                     \
        int lenB = (HASB) ? (LENB) : 0;                                        \
        float a0=0.f,a1=0.f,a2=0.f,a3=0.f,a4=0.f,a5=0.f,a6=0.f,a7=0.f;         \
        float q0=0.f,q1=0.f,q2=0.f,q3=0.f,q4=0.f,q5=0.f,q6=0.f,q7=0.f;         \
        int eA = 0, eB = 0;                                                    \
        while (eA + 8 <= lenA && eB + 8 <= lenB) {      /* 16 in flight */     \
            int4 iA0 = *(const int4*)&rowA[eA];                                \
            int4 iA1 = *(const int4*)&rowA[eA + 4];                            \
            int4 iB0 = *(const int4*)&rowB[eB];                                \
            int4 iB1 = *(const int4*)&rowB[eB + 4];                            \
            float4 rA0 = H16[(size_t)iA0.x * 8 + l8];                          \
            float4 rA1 = H16[(size_t)iA0.y * 8 + l8];                          \
            float4 rA2 = H16[(size_t)iA0.z * 8 + l8];                          \
            float4 rA3 = H16[(size_t)iA0.w * 8 + l8];                          \
            float4 rA4 = H16[(size_t)iA1.x * 8 + l8];                          \
            float4 rA5 = H16[(size_t)iA1.y * 8 + l8];                          \
            float4 rA6 = H16[(size_t)iA1.z * 8 + l8];                          \
            float4 rA7 = H16[(size_t)iA1.w * 8 + l8];                          \
            float4 rB0 = H16[(size_t)iB0.x * 8 + l8];                          \
            float4 rB1 = H16[(size_t)iB0.y * 8 + l8];                          \
            float4 rB2 = H16[(size_t)iB0.z * 8 + l8];                          \
            float4 rB3 = H16[(size_t)iB0.w * 8 + l8];                          \
            float4 rB4 = H16[(size_t)iB1.x * 8 + l8];                          \
            float4 rB5 = H16[(size_t)iB1.y * 8 + l8];                          \
            float4 rB6 = H16[(size_t)iB1.z * 8 + l8];                          \
            float4 rB7 = H16[(size_t)iB1.w * 8 + l8];                          \
            ACCA(rA0); ACCB(rB0); ACCA(rA1); ACCB(rB1);                        \
            ACCA(rA2); ACCB(rB2); ACCA(rA3); ACCB(rB3);                        \
            ACCA(rA4); ACCB(rB4); ACCA(rA5); ACCB(rB5);                        \
            ACCA(rA6); ACCB(rB6); ACCA(rA7); ACCB(rB7);                        \
            eA += 8; eB += 8;                                                  \
        }                                                                      \
        while (eA + 4 <= lenA && eB + 4 <= lenB) {      /* 8 in flight */      \
            LD4A(eA); LD4B(eB);                                                \
            ACCA(rA0); ACCB(rB0); ACCA(rA1); ACCB(rB1);                        \
            ACCA(rA2); ACCB(rB2); ACCA(rA3); ACCB(rB3);                        \
            eA += 4; eB += 4;                                                  \
        }                                                                      \
        for (; eA + 4 <= lenA; eA += 4) {                                      \
            LD4A(eA);                                                          \
            ACCA(rA0); ACCA(rA1); ACCA(rA2); ACCA(rA3);                        \
        }                                                                      \
        for (; eA < lenA; eA++) {                                              \
            float4 r0 = H16[(size_t)rowA[eA] * 8 + l8];                        \
            ACCA(r0);                                                          \
        }                                                                      \
        { float4 rs = H16[(size_t)(NODEA) * 8 + l8]; ACCA(rs); }               \
        float dA_ = (DVA);                                                     \
        p0 += fmaxf(a0 * dA_ + b2a.x, 0.f);                                    \
        p1 += fmaxf(a1 * dA_ + b2a.y, 0.f);                                    \
        p2 += fmaxf(a2 * dA_ + b2a.z, 0.f);                                    \
        p3 += fmaxf(a3 * dA_ + b2a.w, 0.f);                                    \
        p4 += fmaxf(a4 * dA_ + b2b.x, 0.f);                                    \
        p5 += fmaxf(a5 * dA_ + b2b.y, 0.f);                                    \
        p6 += fmaxf(a6 * dA_ + b2b.z, 0.f);                                    \
        p7 += fmaxf(a7 * dA_ + b2b.w, 0.f);                                    \
        if (HASB) {                                                            \
            for (; eB + 4 <= lenB; eB += 4) {                                  \
                LD4B(eB);                                                      \
                ACCB(rB0); ACCB(rB1); ACCB(rB2); ACCB(rB3);                    \
            }                                                                  \
            for (; eB < lenB; eB++) {                                          \
                float4 r0 = H16[(size_t)rowB[eB] * 8 + l8];                    \
                ACCB(r0);                                                      \
            }                                                                  \
            { float4 rs = H16[(size_t)(NODEB) * 8 + l8]; ACCB(rs); }           \
            float dB_ = (DVB);                                                 \
            p0 += fmaxf(q0 * dB_ + b2a.x, 0.f);                                \
            p1 += fmaxf(q1 * dB_ + b2a.y, 0.f);                                \
            p2 += fmaxf(q2 * dB_ + b2a.z, 0.f);                                \
            p3 += fmaxf(q3 * dB_ + b2a.w, 0.f);                                \
            p4 += fmaxf(q4 * dB_ + b2b.x, 0.f);                                \
            p5 += fmaxf(q5 * dB_ + b2b.y, 0.f);                                \
            p6 += fmaxf(q6 * dB_ + b2b.z, 0.f);                                \
            p7 += fmaxf(q7 * dB_ + b2b.w, 0.f);                                \
        }                                                                      \
    }

    // adjacent-rank pairing: ranks 2*grp and 2*grp+1 have near-equal degrees
    if (n <= NSTG) {                                // staged path (typical)
        for (int r = 2 * grp; r < n; r += 64) {
            int rB = r + 1;
            int lnA = dosort ? (int)ord[r] : r;
            bool hasB = (rB < n);
            int lnB = hasB ? (dosort ? (int)ord[rB] : rB) : lnA;
            DUAL_BODY(&sbkt[lnA][0], scnt[lnA], sdinv[lnA], s + lnA,
                      hasB, &sbkt[lnB][0], scnt[lnB], sdinv[lnB], s + lnB);
        }
    } else {                                        // fallback (~1e-7)
        for (int r = 2 * grp; r < n; r += 64) {
            int rB = r + 1;
            int lnA = dosort ? (int)ord[r] : r;
            bool hasB = (rB < n);
            int lnB = hasB ? (dosort ? (int)ord[rB] : rB) : lnA;
            int nodeA = s + lnA, nodeB = s + lnB;
            DUAL_BODY(bkt + (size_t)nodeA * CAP, min(cnt[nodeA], CAP),
                      dinv[nodeA], nodeA,
                      hasB, bkt + (size_t)nodeB * CAP, min(cnt[nodeB], CAP),
                      dinv[nodeB], nodeB);
        }
    }
#undef DUAL_BODY
#undef LD4A
#undef LD4B
#undef ACCA
#undef ACCB
#undef ACCV
    // reduce the 8 groups within each wave (lane bits 3,4,5), feature-aligned
#pragma unroll
    for (int m = 8; m <= 32; m <<= 1) {
        p0 += __shfl_xor(p0, m); p1 += __shfl_xor(p1, m);
        p2 += __shfl_xor(p2, m); p3 += __shfl_xor(p3, m);
        p4 += __shfl_xor(p4, m); p5 += __shfl_xor(p5, m);
        p6 += __shfl_xor(p6, m); p7 += __shfl_xor(p7, m);
    }
    if ((tid & 63) < 8) {
        float* pw = &pool[w][l8 * 8];
        pw[0] = p0; pw[1] = p1; pw[2] = p2; pw[3] = p3;
        pw[4] = p4; pw[5] = p5; pw[6] = p6; pw[7] = p7;
    }
    __syncthreads();
    // mean pool -> gp
    if (tid < HIDDEN) {
        float inv = 1.0f / fmaxf((float)n, 1.0f);
        gp[tid] = (pool[0][tid] + pool[1][tid] + pool[2][tid] + pool[3][tid]) * inv;
    }
    __syncthreads();
    // z = relu(gp @ W3 + b3)
    if (tid < HIDDEN) {
        float t = b3[tid];
#pragma unroll 8
        for (int k = 0; k < HIDDEN; k++) t += gp[k] * W3[k * HIDDEN + tid];
        gz[tid] = fmaxf(t, 0.f);
    }
    __syncthreads();
    // out = gz @ W4 + b4
    if (tid < OUT_DIM) {
        float t = b4[tid];
#pragma unroll 8
        for (int k = 0; k < HIDDEN; k++) t += gz[k] * W4[k * OUT_DIM + tid];
        out[(size_t)g * OUT_DIM + tid] = t;
    }
}

extern "C" void kernel_launch(void* const* d_in, const int* in_sizes, int n_in,
                              void* d_out, int out_size, void* d_ws, size_t ws_size,
                              hipStream_t stream) {
    const float* x  = (const float*)d_in[0];
    const int*   ei = (const int*)d_in[1];           // [2, E] flattened
    const int*   batch = (const int*)d_in[2];
    const float* W1 = (const float*)d_in[3];
    const float* b1 = (const float*)d_in[4];
    const float* W2 = (const float*)d_in[5];
    const float* b2 = (const float*)d_in[6];
    const float* W3 = (const float*)d_in[7];
    const float* b3 = (const float*)d_in[8];
    const float* W4 = (const float*)d_in[9];
    const float* b4 = (const float*)d_in[10];
    float* out = (float*)d_out;

    const int* src = ei;
    const int* dst = ei + N_EDGES;

    // 256B-aligned workspace carving (keeps hs2h/bkt/xs rows line-aligned;
    // measured 45% FETCH_SIZE reduction on the gather kernel).
    char* wp = (char*)d_ws;
    auto carve = [&](size_t bytes) -> void* {
        void* p = (void*)wp;
        wp += (bytes + 255) & ~(size_t)255;
        return p;
    };
    int*    cnt     = (int*)carve((size_t)N_NODES * sizeof(int));
    int*    bkt     = (int*)carve((size_t)N_NODES * CAP * sizeof(int));
    float*  dinv    = (float*)carve((size_t)N_NODES * sizeof(float));
    __half* hs2h    = (__half*)carve((size_t)N_NODES * HIDDEN * sizeof(__half));
    __half* xs      = (__half*)carve((size_t)N_NODES * 8 * sizeof(__half));
    int*    epart   = (int*)carve((size_t)NBIN * CAPBIN * sizeof(int));
    int*    gs      = (int*)carve((size_t)(N_GRAPHS + 1) * sizeof(int));
    int*    gcursor = (int*)carve((size_t)NBIN * sizeof(int));

    hipMemsetAsync(gcursor, 0, (size_t)NBIN * sizeof(int), stream);
    k_part2<<<NA, 256, 0, stream>>>(src, dst, batch, gcursor, epart, gs);
    k_build<<<NBIN, 256, 0, stream>>>(epart, gcursor, x, cnt, bkt, dinv, xs);
    k_g5l12<<<(N_NODES + 63) / 64, 256, 0, stream>>>(cnt, bkt, xs, W1, b1, W2,
                                                     dinv, hs2h);
    k_g2ph<<<N_GRAPHS, 256, 0, stream>>>(cnt, bkt, hs2h, dinv, gs, b2,
                                         W3, b3, W4, b4, out);
}

// Round 9
// 157.912 us; speedup vs baseline: 1.0288x; 1.0288x over previous
//
#include <hip/hip_runtime.h>
#include <hip/hip_fp16.h>

#define N_NODES  100000
#define N_EDGES  1000000
#define N_GRAPHS 2048
#define IN_DIM   5
#define HIDDEN   64
#define OUT_DIM  128
#define CAP      32    // bucket capacity; in-degree ~ Poisson(10), P(>=33)~5e-9/node
#define NA       512   // blocks in partition pass
#define PART     256   // nodes per partition (= 2^8, matches dst>>8)
#define NBIN     391   // ceil(N_NODES/PART)
#define CAPBIN   4096  // epart slab per bin (>>10 sigma of Binom bin count)
#define LSTR     72    // LDS row stride in halves (144 B: 16B-aligned, 2-way banks)
#define MAXN     192   // max nodes/graph for degree sort (mean 48.8, sd 7)
#define NSTG     96    // max nodes/graph for LDS bucket staging (6.7 sigma)
#define EPT      8     // edges per thread in k_part2 (ceil(1M/131072))

typedef _Float16 f16x8 __attribute__((ext_vector_type(8)));
typedef float    f32x4 __attribute__((ext_vector_type(4)));

// ---------------------------------------------------------------------------
// NOTE (R3): device-scope atomic cnt + dependent scattered 4B stores = 85us
// (write-allocate thrash).  Keep the LDS multisplit.  Do not re-try.
// NOTE (R5): launch-count reduction was NEUTRAL (graph capture).
// NOTE (R6): degree-sorted node order won ~4.6us (wave divergence).
// NOTE (R7): LDS bucket staging won ~2.8us (index loads off critical path).
// NOTE (R8): dual-node interleave REGRESSED (−2us): per-wave in-flight was
// not the limiter (gathers are cache-cold traffic-bound; the 268MB harness
// re-poison flushes L2/L3 every iteration).  Reverted.  Do not re-try ILP
// widening on the gather loops.
// R9: wave-parallel prefix scan in the sort prologues (was serial tid==0,
// 33 LDS round-trips on every block's critical path).
// ---------------------------------------------------------------------------

// pass A: fused {graph-ranges + per-block histogram + slab reserve + scatter}.
// Edges register-cached between passes: each thread owns <= EPT edges.
__global__ void __launch_bounds__(256) k_part2(
        const int* __restrict__ src, const int* __restrict__ dst,
        const int* __restrict__ batch, int* __restrict__ gcursor,
        int* __restrict__ epart, int* __restrict__ gs) {
    __shared__ int h[NBIN];
    __shared__ int off[NBIN];
    int t = threadIdx.x, b = blockIdx.x;

    // folded k_ranges: gs[g] = first node with batch >= g (batch sorted)
    int gid = b * 256 + t;
    if (gid < N_NODES) {
        int bi = batch[gid];
        int bp = (gid == 0) ? -1 : batch[gid - 1];
        for (int g = bp + 1; g <= bi; g++) gs[g] = gid;
        if (gid == N_NODES - 1)
            for (int g = bi + 1; g <= N_GRAPHS; g++) gs[g] = N_NODES;
    }

    for (int i = t; i < NBIN; i += 256) h[i] = 0;
    __syncthreads();
    int ebin[EPT], epay[EPT];
    int ebase = b * 256 + t;
#pragma unroll
    for (int i = 0; i < EPT; i++) {
        int e = ebase + i * (NA * 256);
        ebin[i] = -1;
        if (e < N_EDGES) {
            int d = dst[e];
            ebin[i] = d >> 8;
            epay[i] = ((d & (PART - 1)) << 17) | src[e];
            atomicAdd(&h[ebin[i]], 1);              // LDS atomic
        }
    }
    __syncthreads();
    for (int i = t; i < NBIN; i += 256) {
        int c = h[i];
        int base = c ? atomicAdd(&gcursor[i], c) : 0;   // global slab reserve
        off[i] = i * CAPBIN + base;
    }
    __syncthreads();
#pragma unroll
    for (int i = 0; i < EPT; i++) {
        if (ebin[i] >= 0) {
            int pos = atomicAdd(&off[ebin[i]], 1);  // LDS cursor
            if (pos < (ebin[i] + 1) * CAPBIN)       // overflow guard (~1e-20)
                epart[pos] = epay[i];
        }
    }
}

// pass B: per-partition bucket build fully in LDS + fused prep (dinv, xs fp16)
__global__ void __launch_bounds__(256) k_build(
        const int* __restrict__ epart, const int* __restrict__ bincnt,
        const float* __restrict__ x, int* __restrict__ cnt, int* __restrict__ bkt,
        float* __restrict__ dinv, __half* __restrict__ xs) {
    __shared__ int lcnt[PART];
    __shared__ int lrows[PART * CAP];               // 32 KB
    int t = threadIdx.x, b = blockIdx.x;
    int base = b * PART;
    for (int i = t; i < PART; i += 256) lcnt[i] = 0;
    __syncthreads();
    int estart = b * CAPBIN;
    int eend = estart + min(bincnt[b], CAPBIN);
    for (int i = estart + t; i < eend; i += 256) {
        int ed = epart[i];
        int ln = ed >> 17;
        int c = atomicAdd(&lcnt[ln], 1);            // LDS atomic
        if (c < CAP) lrows[ln * CAP + c] = ed & 0x1FFFF;
    }
    __syncthreads();
    int gbase = base * CAP;
    int lim = min(PART * CAP, N_NODES * CAP - gbase);
    for (int i = t; i < lim; i += 256) bkt[gbase + i] = lrows[i];
    for (int n = t; n < PART; n += 256) {
        int g = base + n;
        if (g < N_NODES) {
            int c = lcnt[n];
            cnt[g] = c;
            float d = rsqrtf(1.0f + (float)c);
            dinv[g] = d;
            union { __half h[8]; float4 f4; } u;
#pragma unroll
            for (int k = 0; k < 8; k++)
                u.h[k] = __float2half((k < IN_DIM) ? x[g * IN_DIM + k] * d : 0.0f);
            ((float4*)xs)[g] = u.f4;                // one 16B store
        }
    }
}

// fused layer-1 gather + layer-1 linear + layer-2 linear (MFMA). 64 nodes/block.
// Degree-sorted node order; block's 64 bkt rows staged into the (temporally
// dead) lh1 LDS region via one coalesced sweep.
__global__ void __launch_bounds__(256) k_g5l12(
        const int* __restrict__ cnt, const int* __restrict__ bkt,
        const __half* __restrict__ xs,
        const float* __restrict__ W1, const float* __restrict__ b1,
        const float* __restrict__ W2, const float* __restrict__ dinv,
        __half* __restrict__ hs2h) {
    __shared__ __align__(16) _Float16 lh1[64 * LSTR];   // h1 (phase>=1); bkt stage (phase A)
    __shared__ __align__(16) _Float16 lw2[64 * LSTR];   // W2 transposed: lw2[n*LSTR + k]
    __shared__ float la5[64][8];          // aggregated layer-1 input
    __shared__ unsigned short ordn[64];   // degree-sorted node permutation
    __shared__ int dsh[CAP + 1];
    __shared__ int sdeg[64];
    int tid = threadIdx.x;
    int w = tid >> 6, l = tid & 63;
    int nodeBase = blockIdx.x * 64;

    // W2 staging: 4 float4 loads/thread (was 16 scalar loads)
#pragma unroll
    for (int i = 0; i < 4; i++) {
        int idx = tid + i * 256;          // 0..1023 float4s
        float4 wv = ((const float4*)W2)[idx];
        int k = idx >> 4, n4 = (idx & 15) * 4;
        lw2[(n4 + 0) * LSTR + k] = (_Float16)wv.x;
        lw2[(n4 + 1) * LSTR + k] = (_Float16)wv.y;
        lw2[(n4 + 2) * LSTR + k] = (_Float16)wv.z;
        lw2[(n4 + 3) * LSTR + k] = (_Float16)wv.w;
    }

    // stage this block's 64 bkt rows (8 KB contiguous) into lh1's space
    int* sbkt5 = (int*)lh1;               // 64*CAP ints = 8 KB (lh1 is 9.2 KB)
    {
        const int4* gb = (const int4*)(bkt + (size_t)nodeBase * CAP);
        int4* sb = (int4*)sbkt5;
        int lim4 = min(64, N_NODES - nodeBase) * (CAP / 4);
        for (int i = tid; i < lim4; i += 256) sb[i] = gb[i];
    }

    // counting sort of the block's 64 nodes by degree
    if (tid <= CAP) dsh[tid] = 0;
    __syncthreads();
    int mydeg = 0;
    if (tid < 64) {
        int g = nodeBase + tid;
        mydeg = (g < N_NODES) ? min(cnt[g], CAP) : 0;
        sdeg[tid] = mydeg;
        atomicAdd(&dsh[mydeg], 1);
    }
    __syncthreads();
    if (tid < 64) {                       // wave-parallel exclusive scan
        int orig = (tid <= CAP) ? dsh[tid] : 0;
        int v = orig;
#pragma unroll
        for (int off = 1; off < 64; off <<= 1) {
            int u = __shfl_up(v, off);
            if (tid >= off) v += u;
        }
        if (tid <= CAP) dsh[tid] = v - orig;
    }
    __syncthreads();
    if (tid < 64) { int pos = atomicAdd(&dsh[mydeg], 1); ordn[pos] = tid; }
    __syncthreads();   // also covers sbkt5 staging

    // phase A: 4 lanes per node split the edge list; indices from LDS;
    // each lane loads the FULL 16B xs row (float4); shfl butterfly merge.
    {
        int g4 = l >> 2, l4 = l & 3;      // node-in-wave, lane-in-node
        int lnm = ordn[w * 16 + g4];      // degree-sorted assignment
        int g = nodeBase + lnm;
        float s0 = 0.f, s1 = 0.f, s2 = 0.f, s3 = 0.f;
        float s4 = 0.f, s5 = 0.f, s6 = 0.f, s7 = 0.f;
        if (g < N_NODES) {
            const float4* XS4 = (const float4*)xs;   // one row = one float4
            int len = sdeg[lnm];
            const int* row = sbkt5 + lnm * CAP;      // LDS indices
#define XACC(r) { const __half2* hp_ = (const __half2*)&(r);                   \
            float2 u0_ = __half22float2(hp_[0]), u1_ = __half22float2(hp_[1]); \
            float2 u2_ = __half22float2(hp_[2]), u3_ = __half22float2(hp_[3]); \
            s0 += u0_.x; s1 += u0_.y; s2 += u1_.x; s3 += u1_.y;                \
            s4 += u2_.x; s5 += u2_.y; s6 += u3_.x; s7 += u3_.y; }
            int e = l4;
            for (; e + 4 < len; e += 8) {            // 2 outstanding 16B loads
                float4 r0 = XS4[row[e]];
                float4 r1 = XS4[row[e + 4]];
                XACC(r0); XACC(r1);
            }
            if (e < len) { float4 r0 = XS4[row[e]]; XACC(r0); }
            if (l4 == 0) { float4 rs = XS4[g]; XACC(rs); }   // self loop
#undef XACC
        }
        // merge the 4 lane-partials of each node (lane bits 0,1)
#pragma unroll
        for (int m = 1; m <= 2; m <<= 1) {
            s0 += __shfl_xor(s0, m); s1 += __shfl_xor(s1, m);
            s2 += __shfl_xor(s2, m); s3 += __shfl_xor(s3, m);
            s4 += __shfl_xor(s4, m); s5 += __shfl_xor(s5, m);
            s6 += __shfl_xor(s6, m); s7 += __shfl_xor(s7, m);
        }
        if (l4 == 0) {
            float d = (g < N_NODES) ? dinv[g] : 0.f;
            la5[lnm][0] = s0 * d; la5[lnm][1] = s1 * d;
            la5[lnm][2] = s2 * d; la5[lnm][3] = s3 * d;
            la5[lnm][4] = s4 * d; la5[lnm][5] = s5 * d;
            la5[lnm][6] = s6 * d; la5[lnm][7] = s7 * d;
        }
    }
    __syncthreads();   // la5 cross-wave; sbkt5 reads done -> lh1 reusable

    // phase 1: wave w computes h1 for its 16 nodes, lane = feature
    int f = l;
    float b1v = b1[f];
    float w1v[IN_DIM];
#pragma unroll
    for (int k = 0; k < IN_DIM; k++) w1v[k] = W1[k * HIDDEN + f];
    for (int i = 0; i < 16; i++) {
        int ln = w * 16 + i;
        float t1 = b1v;
#pragma unroll
        for (int k = 0; k < IN_DIM; k++)
            t1 += la5[ln][k] * w1v[k];
        lh1[ln * LSTR + f] = (_Float16)fmaxf(t1, 0.f);
    }
    __syncthreads();

    // phase 2: wave w owns row-block w (16 nodes) x 4 col-tiles, K=64
    int quad = l >> 4, m16 = l & 15;
    f32x4 acc0 = {0.f, 0.f, 0.f, 0.f};
    f32x4 acc1 = {0.f, 0.f, 0.f, 0.f};
    f32x4 acc2 = {0.f, 0.f, 0.f, 0.f};
    f32x4 acc3 = {0.f, 0.f, 0.f, 0.f};
#pragma unroll
    for (int kc = 0; kc < 2; kc++) {
        f16x8 a = *(const f16x8*)&lh1[(w * 16 + m16) * LSTR + kc * 32 + quad * 8];
        f16x8 b0 = *(const f16x8*)&lw2[(0 * 16 + m16) * LSTR + kc * 32 + quad * 8];
        f16x8 b1f = *(const f16x8*)&lw2[(1 * 16 + m16) * LSTR + kc * 32 + quad * 8];
        f16x8 b2 = *(const f16x8*)&lw2[(2 * 16 + m16) * LSTR + kc * 32 + quad * 8];
        f16x8 b3 = *(const f16x8*)&lw2[(3 * 16 + m16) * LSTR + kc * 32 + quad * 8];
        acc0 = __builtin_amdgcn_mfma_f32_16x16x32_f16(a, b0, acc0, 0, 0, 0);
        acc1 = __builtin_amdgcn_mfma_f32_16x16x32_f16(a, b1f, acc1, 0, 0, 0);
        acc2 = __builtin_amdgcn_mfma_f32_16x16x32_f16(a, b2, acc2, 0, 0, 0);
        acc3 = __builtin_amdgcn_mfma_f32_16x16x32_f16(a, b3, acc3, 0, 0, 0);
    }
#pragma unroll
    for (int i = 0; i < 4; i++) {
        int g = nodeBase + w * 16 + quad * 4 + i;
        if (g >= N_NODES) continue;
        float dv = dinv[g];
        __half* row = hs2h + (size_t)g * HIDDEN + m16;
        row[0]  = __float2half(acc0[i] * dv);
        row[16] = __float2half(acc1[i] * dv);
        row[32] = __float2half(acc2[i] * dv);
        row[48] = __float2half(acc3[i] * dv);
    }
}

// layer-2 gather + relu+b2 + pool + FUSED HEAD MLP.  Graph-per-block,
// register pooling, zero atomics, degree-sorted node order, and the graph's
// bucket slab (contiguous in bkt) staged into LDS via one coalesced sweep.
__global__ void __launch_bounds__(256) k_g2ph(
        const int* __restrict__ cnt, const int* __restrict__ bkt,
        const __half* __restrict__ hs2h, const float* __restrict__ dinv,
        const int* __restrict__ gs, const float* __restrict__ b2,
        const float* __restrict__ W3, const float* __restrict__ b3,
        const float* __restrict__ W4, const float* __restrict__ b4,
        float* __restrict__ out) {
    __shared__ __align__(16) int sbkt[NSTG][CAP];   // 12 KB staged indices
    __shared__ int   scnt[NSTG];
    __shared__ float sdinv[NSTG];
    __shared__ float pool[4][HIDDEN];               // 1 KB
    __shared__ float gp[HIDDEN];
    __shared__ float gz[HIDDEN];
    __shared__ unsigned short ord[MAXN];
    __shared__ int dsh[CAP + 1];
    int g = blockIdx.x, tid = threadIdx.x;
    int grp = tid >> 3, l8 = tid & 7;               // 32 groups x 8 lanes
    int w = tid >> 6;
    int s = gs[g], e = gs[g + 1];
    int n = e - s;
    int nst = min(n, NSTG);
    bool dosort = (n <= MAXN);

    // coalesced stage of the graph's bucket slab + cnt + dinv
    {
        const int4* gb = (const int4*)(bkt + (size_t)s * CAP);
        int4* sb = (int4*)&sbkt[0][0];
        int tot = nst * (CAP / 4);
        for (int i = tid; i < tot; i += 256) sb[i] = gb[i];
    }
    for (int i = tid; i < nst; i += 256) {
        scnt[i]  = min(cnt[s + i], CAP);
        sdinv[i] = dinv[s + i];
    }
    if (tid <= CAP) dsh[tid] = 0;
    __syncthreads();

    // counting sort of the graph's nodes by degree (order-free reductions)
    int mydeg = 0;
    if (dosort && tid < n) {
        mydeg = (tid < nst) ? scnt[tid] : min(cnt[s + tid], CAP);
        atomicAdd(&dsh[mydeg], 1);
    }
    __syncthreads();
    if (tid < 64) {                       // wave-parallel exclusive scan
        int orig = (tid <= CAP) ? dsh[tid] : 0;
        int v = orig;
#pragma unroll
        for (int off = 1; off < 64; off <<= 1) {
            int u = __shfl_up(v, off);
            if (tid >= off) v += u;
        }
        if (tid <= CAP) dsh[tid] = v - orig;
    }
    __syncthreads();
    if (dosort && tid < n) { int pos = atomicAdd(&dsh[mydeg], 1); ord[pos] = tid; }
    __syncthreads();

    const float4* H16 = (const float4*)hs2h;        // row = 8 float4 (aligned)
    float4 b2a = ((const float4*)b2)[l8 * 2];
    float4 b2b = ((const float4*)b2)[l8 * 2 + 1];
    float p0 = 0.f, p1 = 0.f, p2 = 0.f, p3 = 0.f;
    float p4 = 0.f, p5 = 0.f, p6 = 0.f, p7 = 0.f;

#define ACCA(r) { const __half2* hp_ = (const __half2*)&(r);               \
        float2 u0_ = __half22float2(hp_[0]), u1_ = __half22float2(hp_[1]); \
        float2 u2_ = __half22float2(hp_[2]), u3_ = __half22float2(hp_[3]); \
        a0 += u0_.x; a1 += u0_.y; a2 += u1_.x; a3 += u1_.y;                \
        a4 += u2_.x; a5 += u2_.y; a6 += u3_.x; a7 += u3_.y; }
#define ACCC(r) { const __half2* hp_ = (const __half2*)&(r);               \
        float2 u0_ = __half22float2(hp_[0]), u1_ = __half22float2(hp_[1]); \
        float2 u2_ = __half22float2(hp_[2]), u3_ = __half22float2(hp_[3]); \
        c0 += u0_.x; c1 += u0_.y; c2 += u1_.x; c3 += u1_.y;                \
        c4 += u2_.x; c5 += u2_.y; c6 += u3_.x; c7 += u3_.y; }

#define NODE_BODY(ROW, LEN, DV, NODE)                                      \
    {                                                                      \
        float a0 = 0.f, a1 = 0.f, a2 = 0.f, a3 = 0.f;                      \
        float a4 = 0.f, a5 = 0.f, a6 = 0.f, a7 = 0.f;                      \
        float c0 = 0.f, c1 = 0.f, c2 = 0.f, c3 = 0.f;                      \
        float c4 = 0.f, c5 = 0.f, c6 = 0.f, c7 = 0.f;                      \
        int ee = 0;                                                        \
        for (; ee + 8 <= (LEN); ee += 8) {                                 \
            int4 i0 = *(const int4*)&(ROW)[ee];                            \
            int4 i1 = *(const int4*)&(ROW)[ee + 4];                        \
            float4 r0 = H16[(size_t)i0.x * 8 + l8];                        \
            float4 r1 = H16[(size_t)i0.y * 8 + l8];                        \
            float4 r2 = H16[(size_t)i0.z * 8 + l8];                        \
            float4 r3 = H16[(size_t)i0.w * 8 + l8];                        \
            float4 r4 = H16[(size_t)i1.x * 8 + l8];                        \
            float4 r5 = H16[(size_t)i1.y * 8 + l8];                        \
            float4 r6 = H16[(size_t)i1.z * 8 + l8];                        \
            float4 r7 = H16[(size_t)i1.w * 8 + l8];                        \
            ACCA(r0); ACCC(r1); ACCA(r2); ACCC(r3);                        \
            ACCA(r4); ACCC(r5); ACCA(r6); ACCC(r7);                        \
        }                                                                  \
        if (ee + 4 <= (LEN)) {                                             \
            int4 i0 = *(const int4*)&(ROW)[ee];                            \
            float4 r0 = H16[(size_t)i0.x * 8 + l8];                        \
            float4 r1 = H16[(size_t)i0.y * 8 + l8];                        \
            float4 r2 = H16[(size_t)i0.z * 8 + l8];                        \
            float4 r3 = H16[(size_t)i0.w * 8 + l8];                        \
            ACCA(r0); ACCC(r1); ACCA(r2); ACCC(r3);                        \
            ee += 4;                                                       \
        }                                                                  \
        for (; ee < (LEN); ee++) {                                         \
            float4 r0 = H16[(size_t)(ROW)[ee] * 8 + l8];                   \
            ACCA(r0);                                                      \
        }                                                                  \
        { float4 rs = H16[(size_t)(NODE) * 8 + l8]; ACCA(rs); }            \
        float dv_ = (DV);                                                  \
        p0 += fmaxf((a0 + c0) * dv_ + b2a.x, 0.f);                         \
        p1 += fmaxf((a1 + c1) * dv_ + b2a.y, 0.f);                         \
        p2 += fmaxf((a2 + c2) * dv_ + b2a.z, 0.f);                         \
        p3 += fmaxf((a3 + c3) * dv_ + b2a.w, 0.f);                         \
        p4 += fmaxf((a4 + c4) * dv_ + b2b.x, 0.f);                         \
        p5 += fmaxf((a5 + c5) * dv_ + b2b.y, 0.f);                         \
        p6 += fmaxf((a6 + c6) * dv_ + b2b.z, 0.f);                         \
        p7 += fmaxf((a7 + c7) * dv_ + b2b.w, 0.f);                         \
    }

    if (n <= NSTG) {                                // staged path (typical)
        for (int r = grp; r < n; r += 32) {
            int ln = dosort ? (int)ord[r] : r;
            const int* row = &sbkt[ln][0];          // LDS indices
            NODE_BODY(row, scnt[ln], sdinv[ln], s + ln);
        }
    } else {                                        // fallback (~1e-7)
        for (int r = grp; r < n; r += 32) {
            int ln = dosort ? (int)ord[r] : r;
            int node = s + ln;
            const int* row = bkt + (size_t)node * CAP;
            NODE_BODY(row, min(cnt[node], CAP), dinv[node], node);
        }
    }
#undef NODE_BODY
#undef ACCA
#undef ACCC
    // reduce the 8 groups within each wave (lane bits 3,4,5), feature-aligned
#pragma unroll
    for (int m = 8; m <= 32; m <<= 1) {
        p0 += __shfl_xor(p0, m); p1 += __shfl_xor(p1, m);
        p2 += __shfl_xor(p2, m); p3 += __shfl_xor(p3, m);
        p4 += __shfl_xor(p4, m); p5 += __shfl_xor(p5, m);
        p6 += __shfl_xor(p6, m); p7 += __shfl_xor(p7, m);
    }
    if ((tid & 63) < 8) {
        float* pw = &pool[w][l8 * 8];
        pw[0] = p0; pw[1] = p1; pw[2] = p2; pw[3] = p3;
        pw[4] = p4; pw[5] = p5; pw[6] = p6; pw[7] = p7;
    }
    __syncthreads();
    // mean pool -> gp
    if (tid < HIDDEN) {
        float inv = 1.0f / fmaxf((float)n, 1.0f);
        gp[tid] = (pool[0][tid] + pool[1][tid] + pool[2][tid] + pool[3][tid]) * inv;
    }
    __syncthreads();
    // z = relu(gp @ W3 + b3)
    if (tid < HIDDEN) {
        float t = b3[tid];
#pragma unroll 8
        for (int k = 0; k < HIDDEN; k++) t += gp[k] * W3[k * HIDDEN + tid];
        gz[tid] = fmaxf(t, 0.f);
    }
    __syncthreads();
    // out = gz @ W4 + b4
    if (tid < OUT_DIM) {
        float t = b4[tid];
#pragma unroll 8
        for (int k = 0; k < HIDDEN; k++) t += gz[k] * W4[k * OUT_DIM + tid];
        out[(size_t)g * OUT_DIM + tid] = t;
    }
}

extern "C" void kernel_launch(void* const* d_in, const int* in_sizes, int n_in,
                              void* d_out, int out_size, void* d_ws, size_t ws_size,
                              hipStream_t stream) {
    const float* x  = (const float*)d_in[0];
    const int*   ei = (const int*)d_in[1];           // [2, E] flattened
    const int*   batch = (const int*)d_in[2];
    const float* W1 = (const float*)d_in[3];
    const float* b1 = (const float*)d_in[4];
    const float* W2 = (const float*)d_in[5];
    const float* b2 = (const float*)d_in[6];
    const float* W3 = (const float*)d_in[7];
    const float* b3 = (const float*)d_in[8];
    const float* W4 = (const float*)d_in[9];
    const float* b4 = (const float*)d_in[10];
    float* out = (float*)d_out;

    const int* src = ei;
    const int* dst = ei + N_EDGES;

    // 256B-aligned workspace carving (keeps hs2h/bkt/xs rows line-aligned;
    // measured 45% FETCH_SIZE reduction on the gather kernel).
    char* wp = (char*)d_ws;
    auto carve = [&](size_t bytes) -> void* {
        void* p = (void*)wp;
        wp += (bytes + 255) & ~(size_t)255;
        return p;
    };
    int*    cnt     = (int*)carve((size_t)N_NODES * sizeof(int));
    int*    bkt     = (int*)carve((size_t)N_NODES * CAP * sizeof(int));
    float*  dinv    = (float*)carve((size_t)N_NODES * sizeof(float));
    __half* hs2h    = (__half*)carve((size_t)N_NODES * HIDDEN * sizeof(__half));
    __half* xs      = (__half*)carve((size_t)N_NODES * 8 * sizeof(__half));
    int*    epart   = (int*)carve((size_t)NBIN * CAPBIN * sizeof(int));
    int*    gs      = (int*)carve((size_t)(N_GRAPHS + 1) * sizeof(int));
    int*    gcursor = (int*)carve((size_t)NBIN * sizeof(int));

    hipMemsetAsync(gcursor, 0, (size_t)NBIN * sizeof(int), stream);
    k_part2<<<NA, 256, 0, stream>>>(src, dst, batch, gcursor, epart, gs);
    k_build<<<NBIN, 256, 0, stream>>>(epart, gcursor, x, cnt, bkt, dinv, xs);
    k_g5l12<<<(N_NODES + 63) / 64, 256, 0, stream>>>(cnt, bkt, xs, W1, b1, W2,
                                                     dinv, hs2h);
    k_g2ph<<<N_GRAPHS, 256, 0, stream>>>(cnt, bkt, hs2h, dinv, gs, b2,
                                         W3, b3, W4, b4, out);
}